// Round 1
// baseline (52.502 us; speedup 1.0000x reference)
//
#include <hip/hip_runtime.h>
#include <hip/hip_bf16.h>
#include <stdint.h>

#define HW 65536
#define BATCH 64
#define KTOP 200
#define K2_THREADS 1024
#define VPT 64   // values per thread: HW / K2_THREADS

// ---------------------------------------------------------------------------
// Kernel 1: diff[b][i] = sum_c (target[b][c][i] - pred[b][c][i])^2
// float4-vectorized, fully coalesced. Grid exactly covers B*HW/4 elements.
// ---------------------------------------------------------------------------
__global__ __launch_bounds__(256) void diff_kernel(
    const float* __restrict__ pred,
    const float* __restrict__ target,
    float* __restrict__ diff)
{
    int n = blockIdx.x * 256 + threadIdx.x;      // 0 .. B*HW/4-1
    int b = n >> 14;                             // / (HW/4=16384)
    int i = n & 16383;
    const float4* p = (const float4*)pred;
    const float4* t = (const float4*)target;
    long base = (long)b * 3 * 16384 + i;
    float4 p0 = p[base];
    float4 p1 = p[base + 16384];
    float4 p2 = p[base + 2 * 16384];
    float4 t0 = t[base];
    float4 t1 = t[base + 16384];
    float4 t2 = t[base + 2 * 16384];
    float4 d;
    {
        float a0 = t0.x - p0.x, a1 = t1.x - p1.x, a2 = t2.x - p2.x;
        d.x = a0 * a0 + a1 * a1 + a2 * a2;
    }
    {
        float a0 = t0.y - p0.y, a1 = t1.y - p1.y, a2 = t2.y - p2.y;
        d.y = a0 * a0 + a1 * a1 + a2 * a2;
    }
    {
        float a0 = t0.z - p0.z, a1 = t1.z - p1.z, a2 = t2.z - p2.z;
        d.z = a0 * a0 + a1 * a1 + a2 * a2;
    }
    {
        float a0 = t0.w - p0.w, a1 = t1.w - p1.w, a2 = t2.w - p2.w;
        d.w = a0 * a0 + a1 * a1 + a2 * a2;
    }
    ((float4*)diff)[(long)b * 16384 + i] = d;
}

// ---------------------------------------------------------------------------
// Kernel 2: one block per batch. Exact radix select of the 200th-largest
// value (values are all >= 0 so uint bit order == float order), then sum of
// top-200 = sum(v > T) + (200 - cnt) * T.
// Three MSB-first histogram passes: bits [31:21], [20:10], [9:0].
// ---------------------------------------------------------------------------
__global__ __launch_bounds__(1024) void select_kernel(
    const float* __restrict__ diffbuf,
    const float* __restrict__ pred,
    const float* __restrict__ target,
    float* __restrict__ partials,
    int fused)
{
    __shared__ uint32_t HA[2048];
    __shared__ uint32_t HB[2048];
    __shared__ uint32_t bcast[2];
    __shared__ float    wsum[16];
    __shared__ uint32_t wcnt[16];

    const int b   = blockIdx.x;
    const int tid = threadIdx.x;

    uint32_t u[VPT];
    if (!fused) {
        const float* row = diffbuf + (long)b * HW;
        #pragma unroll
        for (int j = 0; j < VPT; ++j)
            u[j] = __float_as_uint(row[j * K2_THREADS + tid]);
    } else {
        const float* pb = pred   + (long)b * 3 * HW;
        const float* tb = target + (long)b * 3 * HW;
        #pragma unroll
        for (int j = 0; j < VPT; ++j) {
            int idx = j * K2_THREADS + tid;
            float a0 = tb[idx]          - pb[idx];
            float a1 = tb[HW + idx]     - pb[HW + idx];
            float a2 = tb[2 * HW + idx] - pb[2 * HW + idx];
            u[j] = __float_as_uint(a0 * a0 + a1 * a1 + a2 * a2);
        }
    }

    uint32_t k_need = KTOP;
    uint32_t b1 = 0, b2 = 0, b3 = 0;

    // ---------------- pass macro body (3 instantiations) ----------------
    #define RUN_PASS(BIN_EXPR, PRED_EXPR, OUT_B)                              \
    {                                                                         \
        for (int i = tid; i < 2048; i += K2_THREADS) HA[i] = 0;               \
        __syncthreads();                                                      \
        _Pragma("unroll")                                                     \
        for (int j = 0; j < VPT; ++j) {                                       \
            uint32_t uv = u[j];                                               \
            (void)uv;                                                         \
            if (PRED_EXPR) atomicAdd(&HA[(BIN_EXPR)], 1u);                    \
        }                                                                     \
        __syncthreads();                                                      \
        /* inclusive suffix scan over 2048 bins (Hillis-Steele, ping-pong) */ \
        uint32_t* src = HA;                                                   \
        uint32_t* dst = HB;                                                   \
        for (int d = 1; d < 2048; d <<= 1) {                                  \
            for (int i = tid; i < 2048; i += K2_THREADS) {                    \
                uint32_t v = src[i];                                          \
                if (i + d < 2048) v += src[i + d];                            \
                dst[i] = v;                                                   \
            }                                                                 \
            __syncthreads();                                                  \
            uint32_t* tmp = src; src = dst; dst = tmp;                        \
        }                                                                     \
        /* find max i with S[i] >= k_need */                                  \
        for (int i = tid; i < 2048; i += K2_THREADS) {                        \
            uint32_t Si = src[i];                                             \
            uint32_t Sn = (i + 1 < 2048) ? src[i + 1] : 0;                    \
            if (Si >= k_need && Sn < k_need) {                                \
                bcast[0] = (uint32_t)i;                                       \
                bcast[1] = k_need - Sn;                                       \
            }                                                                 \
        }                                                                     \
        __syncthreads();                                                      \
        OUT_B  = bcast[0];                                                    \
        k_need = bcast[1];                                                    \
        __syncthreads();                                                      \
    }

    // pass 1: bits [31:21]
    RUN_PASS((uv >> 21), true, b1)
    // pass 2: bits [20:10], restricted to bin b1
    RUN_PASS(((uv >> 10) & 0x7FFu), ((uv >> 21) == b1), b2)
    // pass 3: bits [9:0], restricted to prefix (b1<<11)|b2
    {
        uint32_t prefix21 = (b1 << 11) | b2;
        RUN_PASS((uv & 0x3FFu), ((uv >> 10) == prefix21), b3)
    }
    #undef RUN_PASS

    const uint32_t T  = (b1 << 21) | (b2 << 10) | b3;  // exact kth-largest bits
    const float    tv = __uint_as_float(T);

    // final: sum of values strictly greater than T, plus ties at T
    float    s = 0.0f;
    uint32_t c = 0;
    #pragma unroll
    for (int j = 0; j < VPT; ++j) {
        if (u[j] > T) { s += __uint_as_float(u[j]); c += 1u; }
    }
    for (int off = 32; off > 0; off >>= 1) {
        s += __shfl_down(s, off, 64);
        c += __shfl_down(c, off, 64);
    }
    const int wave = tid >> 6, lane = tid & 63;
    if (lane == 0) { wsum[wave] = s; wcnt[wave] = c; }
    __syncthreads();
    if (tid == 0) {
        float    S = 0.0f;
        uint32_t C = 0;
        for (int w = 0; w < 16; ++w) { S += wsum[w]; C += wcnt[w]; }
        partials[b] = S + (float)(KTOP - C) * tv;
    }
}

// ---------------------------------------------------------------------------
// Kernel 3: mean of 64 per-batch top-k sums -> scalar
// ---------------------------------------------------------------------------
__global__ void finalize_kernel(const float* __restrict__ partials,
                                float* __restrict__ out)
{
    float v = partials[threadIdx.x];
    for (int off = 32; off > 0; off >>= 1)
        v += __shfl_down(v, off, 64);
    if (threadIdx.x == 0)
        out[0] = v / (float)(BATCH * KTOP);
}

extern "C" void kernel_launch(void* const* d_in, const int* in_sizes, int n_in,
                              void* d_out, int out_size, void* d_ws, size_t ws_size,
                              hipStream_t stream)
{
    const float* pred   = (const float*)d_in[0];
    const float* target = (const float*)d_in[1];
    float* out = (float*)d_out;

    float* partials = (float*)d_ws;                       // 64 floats
    const size_t diff_off = 256;
    float* diff = (float*)((char*)d_ws + diff_off);
    const size_t need = diff_off + (size_t)BATCH * HW * sizeof(float);

    if (ws_size >= need) {
        diff_kernel<<<4096, 256, 0, stream>>>(pred, target, diff);
        select_kernel<<<BATCH, K2_THREADS, 0, stream>>>(diff, pred, target, partials, 0);
    } else {
        select_kernel<<<BATCH, K2_THREADS, 0, stream>>>(nullptr, pred, target, partials, 1);
    }
    finalize_kernel<<<1, 64, 0, stream>>>(partials, out);
}